// Round 1
// baseline (3809.911 us; speedup 1.0000x reference)
//
#include <hip/hip_runtime.h>

// Problem: B=131072 independent LSTMs, T=40, H=40, input dim 1, FC to C=4 + argmax.
// Design: 1 thread = 1 sample. h/c/h_new in registers (fully unrolled unit loop).
// W_hh/W_ih/biases are wave-uniform with compile-time offsets -> scalar loads,
// FMA uses SGPR operand. FP32 throughout (argmax must match np ref exactly).

#define B_ 131072
#define T_ 40
#define H_ 40
#define C_ 4

__device__ __forceinline__ float fexp2f(float v) { return __builtin_amdgcn_exp2f(v); }
__device__ __forceinline__ float frcpf(float v)  { return __builtin_amdgcn_rcpf(v); }

// sigmoid(x) = 1/(1+2^(-x*log2(e))) ; exact tails: x->+inf => 1, x->-inf => 0
__device__ __forceinline__ float sigmf(float v) {
    return frcpf(1.0f + fexp2f(-1.44269504088896340736f * v));
}
// tanh(x) = 1 - 2/(2^(2x*log2(e)) + 1) ; exact tails: +/-1
__device__ __forceinline__ float tanhf_(float v) {
    return 1.0f - 2.0f * frcpf(1.0f + fexp2f(2.88539008177792681472f * v));
}

__global__ __launch_bounds__(256, 2)
void lstm_fused_kernel(const float* __restrict__ x,
                       const float* __restrict__ W_ih,   // (160,1) -> w_in[160]
                       const float* __restrict__ W_hh,   // (160,40) row-major
                       const float* __restrict__ b_ih,   // (160,)
                       const float* __restrict__ b_hh,   // (160,)
                       const float* __restrict__ W_fc,   // (4,40) row-major
                       const float* __restrict__ b_fc,   // (4,)
                       float* __restrict__ out)          // [B*4 logits][B argmax-as-float]
{
    const int b = blockIdx.x * blockDim.x + threadIdx.x;
    const float* xr = x + (long)b * T_;

    float h[H_], c[H_], hn[H_];
#pragma unroll
    for (int j = 0; j < H_; ++j) { h[j] = 0.0f; c[j] = 0.0f; }

    float xt = xr[0];

#pragma unroll 1
    for (int t = 0; t < T_; ++t) {
        // prefetch next step's scalar input (hidden behind the 6400-FMA body)
        const int tn = (t + 1 < T_) ? (t + 1) : (T_ - 1);
        float xnext = xr[tn];

#pragma unroll
        for (int j = 0; j < H_; ++j) {
            // gate pre-activations for hidden unit j: rows j, 40+j, 80+j, 120+j
            float a0 = b_ih[j]        + b_hh[j]        + xt * W_ih[j];
            float a1 = b_ih[40 + j]   + b_hh[40 + j]   + xt * W_ih[40 + j];
            float a2 = b_ih[80 + j]   + b_hh[80 + j]   + xt * W_ih[80 + j];
            float a3 = b_ih[120 + j]  + b_hh[120 + j]  + xt * W_ih[120 + j];
#pragma unroll
            for (int k = 0; k < H_; ++k) {
                const float hk = h[k];
                a0 = fmaf(hk, W_hh[(j)       * H_ + k], a0);
                a1 = fmaf(hk, W_hh[(40 + j)  * H_ + k], a1);
                a2 = fmaf(hk, W_hh[(80 + j)  * H_ + k], a2);
                a3 = fmaf(hk, W_hh[(120 + j) * H_ + k], a3);
            }
            const float ig = sigmf(a0);
            const float fg = sigmf(a1);
            const float gg = tanhf_(a2);
            const float og = sigmf(a3);
            const float cn = fg * c[j] + ig * gg;
            c[j]  = cn;
            hn[j] = og * tanhf_(cn);
        }
#pragma unroll
        for (int j = 0; j < H_; ++j) h[j] = hn[j];
        xt = xnext;
    }

    // FC head: logits[cc] = h . W_fc[cc,:] + b_fc[cc]
    float lg[C_];
#pragma unroll
    for (int cc = 0; cc < C_; ++cc) {
        float a = b_fc[cc];
#pragma unroll
        for (int k = 0; k < H_; ++k) a = fmaf(h[k], W_fc[cc * H_ + k], a);
        lg[cc] = a;
    }

    // logits: coalesced float4 store
    float4 lv = make_float4(lg[0], lg[1], lg[2], lg[3]);
    *reinterpret_cast<float4*>(out + (long)b * C_) = lv;

    // argmax (first occurrence of max, matching jnp.argmax), stored as float
    int am = 0;
    float best = lg[0];
#pragma unroll
    for (int cc = 1; cc < C_; ++cc) {
        if (lg[cc] > best) { best = lg[cc]; am = cc; }
    }
    out[(long)B_ * C_ + b] = (float)am;
}

extern "C" void kernel_launch(void* const* d_in, const int* in_sizes, int n_in,
                              void* d_out, int out_size, void* d_ws, size_t ws_size,
                              hipStream_t stream) {
    const float* x    = (const float*)d_in[0];
    const float* W_ih = (const float*)d_in[1];
    const float* W_hh = (const float*)d_in[2];
    const float* b_ih = (const float*)d_in[3];
    const float* b_hh = (const float*)d_in[4];
    const float* W_fc = (const float*)d_in[5];
    const float* b_fc = (const float*)d_in[6];
    float* out = (float*)d_out;

    dim3 block(256);
    dim3 grid(B_ / 256);
    hipLaunchKernelGGL(lstm_fused_kernel, grid, block, 0, stream,
                       x, W_ih, W_hh, b_ih, b_hh, W_fc, b_fc, out);
}